// Round 13
// baseline (52.481 us; speedup 1.0000x reference)
//
#include <hip/hip_runtime.h>

typedef __attribute__((ext_vector_type(8))) short short8v;   // 8 bf16
typedef __attribute__((ext_vector_type(4))) float f32x4;
typedef unsigned short u16t;

__device__ __forceinline__ u16t f2bf(float f) {
    union { float f; unsigned u; } v; v.f = f;
    unsigned u = v.u;
    return (u16t)((u + 0x7FFFu + ((u >> 16) & 1u)) >> 16);
}
__device__ __forceinline__ float bf2f(u16t u) {
    union { unsigned u; float f; } v; v.u = ((unsigned)u) << 16; return v.f;
}
__device__ __forceinline__ short8v cvt8(const float* p) {
    float4 lo = *(const float4*)p;
    float4 hi = *(const float4*)(p + 4);
    union { uint4 u; short8v s; } r;
    asm("v_cvt_pk_bf16_f32 %0, %1, %2" : "=v"(r.u.x) : "v"(lo.x), "v"(lo.y));
    asm("v_cvt_pk_bf16_f32 %0, %1, %2" : "=v"(r.u.y) : "v"(lo.z), "v"(lo.w));
    asm("v_cvt_pk_bf16_f32 %0, %1, %2" : "=v"(r.u.z) : "v"(hi.x), "v"(hi.y));
    asm("v_cvt_pk_bf16_f32 %0, %1, %2" : "=v"(r.u.w) : "v"(hi.z), "v"(hi.w));
    return r.s;
}
// 8 bf16 from pitch-52 LDS tile (8B-aligned): two b64 loads
__device__ __forceinline__ short8v ld52(const u16t* p) {
    union { uint2 u[2]; short8v s; } r;
    r.u[0] = *(const uint2*)(p);
    r.u[1] = *(const uint2*)(p + 4);
    return r.s;
}

struct Params {
    const float *async_fea, *sync_fea;
    const int *async_adj, *sync_adj;
    const float *Wq[2], *Wk[2], *Wv[2];     // fp32, [agg]
    const float *bq[2], *bk[2], *bv[2];
    const float *Wo[2], *Wm[2], *bo_[2], *bm_[2];
    u16t *Qb, *Kb;             // [agg][1536][256] bf16 row-major
    u16t *VTg;                 // [agg][32][256][48] bf16 (V transposed per batch)
    u16t *Eg, *ETg;            // [agg][b][h][48][48] bf16
    u16t *Wcb;                 // [agg][256][256] bf16: Wc = Wm @ Wo
    float *bcw;                // [agg][256]: bc = Wm @ bo
    float *out;
};

// ---------- Launch 1: QKV MFMA (blocks 0..575, XCD-swizzled) + fold (576..607) ----------
__global__ __launch_bounds__(256) void qkv_fold(Params p)
{
    __shared__ float smem[2304];            // fold: WoT[64][36]
    int bid = blockIdx.x, tid = threadIdx.x;
    int wave = tid >> 6, lane = tid & 63;
    int l15 = lane & 15, g = lane >> 4;

    if (bid < 576) {
        int xcd = bid & 7, idx = bid >> 3;  // idx 0..71
        int agg = xcd >> 2, xcd_in = xcd & 3;
        int ct = idx % 12, rt = (idx / 12) * 4 + xcd_in;   // rt 0..23
        int row0 = rt * 64 + wave * 16;
        int mat = ct >> 2;
        int cbase = (ct & 3) * 64;
        const float* X = agg ? p.async_fea : p.sync_fea;
        const float* W    = (mat == 0) ? p.Wq[agg] : (mat == 1) ? p.Wk[agg] : p.Wv[agg];
        const float* bias = (mat == 0) ? p.bq[agg] : (mat == 1) ? p.bk[agg] : p.bv[agg];
        const float* Xp = X + (row0 + l15) * 256 + g * 8;
        const float* Wp = W + (cbase + l15) * 256 + g * 8;
        f32x4 acc[4] = {{0,0,0,0},{0,0,0,0},{0,0,0,0},{0,0,0,0}};
        #pragma unroll
        for (int kk = 0; kk < 8; ++kk) {
            short8v a = cvt8(Xp + kk * 32);
            #pragma unroll
            for (int j = 0; j < 4; ++j) {
                short8v b = cvt8(Wp + j * 16 * 256 + kk * 32);
                acc[j] = __builtin_amdgcn_mfma_f32_16x16x32_bf16(a, b, acc[j], 0, 0, 0);
            }
        }
        if (mat < 2) {
            u16t* dst = ((mat == 0) ? p.Qb : p.Kb) + agg * 393216;
            #pragma unroll
            for (int j = 0; j < 4; ++j) {
                int c = cbase + j * 16 + l15;
                float bv = bias[c];
                #pragma unroll
                for (int i = 0; i < 4; ++i) {
                    int row = row0 + g * 4 + i;
                    dst[row * 256 + c] = f2bf(acc[j][i] + bv);
                }
            }
        } else {
            u16t* vt = p.VTg + agg * 393216;
            #pragma unroll
            for (int j = 0; j < 4; ++j) {
                int c = cbase + j * 16 + l15;
                float bv = bias[c];
                #pragma unroll
                for (int i = 0; i < 4; ++i) {
                    int row = row0 + g * 4 + i;
                    vt[(row / 48) * 12288 + c * 48 + (row % 48)] = f2bf(acc[j][i] + bv);
                }
            }
        }
    } else {
        // fold: Wc = Wm @ Wo (bf16 out), bc = Wm @ bo   (R4-validated)
        int fid = bid - 576;                 // 0..31
        int agg = fid >> 4, tile = fid & 15;
        int cb = (tile >> 2) * 64, db = (tile & 3) * 64;
        const float* Wm = p.Wm[agg];
        const float* Wo = p.Wo[agg];
        const float* bo = p.bo_[agg];
        u16t* Wcb = p.Wcb + agg * 65536;
        float* bc = p.bcw + agg * 256;
        int crow = cb + wave * 16 + l15;
        const float* Wmp = Wm + crow * 256 + g * 8;
        f32x4 acc[4] = {{0,0,0,0},{0,0,0,0},{0,0,0,0},{0,0,0,0}};
        for (int ch = 0; ch < 8; ++ch) {
            __syncthreads();
            #pragma unroll
            for (int l = 0; l < 8; ++l) {
                int e = l * 256 + tid;
                int ii = e >> 6, dd = e & 63;
                smem[dd * 36 + ii] = Wo[(ch * 32 + ii) * 256 + db + dd];
            }
            __syncthreads();
            short8v a = cvt8(Wmp + ch * 32);
            #pragma unroll
            for (int j = 0; j < 4; ++j) {
                float* sp = &smem[(j * 16 + l15) * 36 + g * 8];
                float4 lo = *(const float4*)sp;
                float4 hi = *(const float4*)(sp + 4);
                union { uint4 u; short8v s; } rb;
                asm("v_cvt_pk_bf16_f32 %0, %1, %2" : "=v"(rb.u.x) : "v"(lo.x), "v"(lo.y));
                asm("v_cvt_pk_bf16_f32 %0, %1, %2" : "=v"(rb.u.y) : "v"(lo.z), "v"(lo.w));
                asm("v_cvt_pk_bf16_f32 %0, %1, %2" : "=v"(rb.u.z) : "v"(hi.x), "v"(hi.y));
                asm("v_cvt_pk_bf16_f32 %0, %1, %2" : "=v"(rb.u.w) : "v"(hi.z), "v"(hi.w));
                acc[j] = __builtin_amdgcn_mfma_f32_16x16x32_bf16(a, rb.s, acc[j], 0, 0, 0);
            }
        }
        #pragma unroll
        for (int j = 0; j < 4; ++j)
            #pragma unroll
            for (int i = 0; i < 4; ++i) {
                int c = cb + wave * 16 + g * 4 + i;
                int d = db + j * 16 + l15;
                Wcb[c * 256 + d] = f2bf(acc[j][i]);
            }
        if ((tile & 3) == 0) {
            int r = tid >> 2, s = tid & 3;
            const float* wmr = Wm + (cb + r) * 256 + s * 64;
            const float* bor = bo + s * 64;
            float a = 0.f;
            #pragma unroll
            for (int i = 0; i < 64; ++i) a += wmr[i] * bor[i];
            a += __shfl_xor(a, 1);
            a += __shfl_xor(a, 2);
            if (s == 0) bc[cb + r] = a;
        }
    }
}

// ---------- Launch 2: scores -> E, ET bf16 (512 blocks, 192 thr), XCD-swizzled ----
__global__ __launch_bounds__(192) void scores_kernel(Params p)
{
    int bid = blockIdx.x;
    int xcd = bid & 7, idx = bid >> 3;        // idx 0..63
    int agg = xcd >> 2, xcd_in = xcd & 3;
    int h = idx & 7, b = (idx >> 3) * 4 + xcd_in;
    int qt = threadIdx.x >> 6, lane = threadIdx.x & 63;
    int l15 = lane & 15, g = lane >> 4;
    const u16t* Qp = p.Qb + agg * 393216 + (b * 48 + qt * 16 + l15) * 256 + h * 32 + g * 8;
    short8v a = *(const short8v*)Qp;
    f32x4 acc[3];
    #pragma unroll
    for (int kt = 0; kt < 3; ++kt) {
        const u16t* Kp = p.Kb + agg * 393216 + (b * 48 + kt * 16 + l15) * 256 + h * 32 + g * 8;
        short8v kb = *(const short8v*)Kp;
        f32x4 z = {0.f, 0.f, 0.f, 0.f};
        acc[kt] = __builtin_amdgcn_mfma_f32_16x16x32_bf16(a, kb, z, 0, 0, 0);
    }
    const float scale = 0.17677669529663687f;  // 1/sqrt(32)
    float sc[3][4], rm[4];
    #pragma unroll
    for (int i = 0; i < 4; ++i) {
        #pragma unroll
        for (int kt = 0; kt < 3; ++kt) sc[kt][i] = acc[kt][i] * scale;
        rm[i] = fmaxf(fmaxf(sc[0][i], sc[1][i]), sc[2][i]);
    }
    #pragma unroll
    for (int m = 1; m <= 8; m <<= 1)
        #pragma unroll
        for (int i = 0; i < 4; ++i) rm[i] = fmaxf(rm[i], __shfl_xor(rm[i], m));
    u16t* Eb  = p.Eg  + (agg * 32 + b) * 18432 + h * 2304;
    u16t* ETb = p.ETg + (agg * 32 + b) * 18432 + h * 2304;
    #pragma unroll
    for (int kt = 0; kt < 3; ++kt)
        #pragma unroll
        for (int i = 0; i < 4; ++i) {
            u16t ev = f2bf(__expf(sc[kt][i] - rm[i]));
            int q = qt * 16 + g * 4 + i, k = kt * 16 + l15;
            Eb[q * 48 + k]  = ev;
            ETb[k * 48 + q] = ev;
        }
}

// ---------- Launch 3: aggregation (256 blocks, 512 thr), XCD-swizzled ----------
// Phases: masks -> A -> B -> C -> G (single GEMM with folded Wc). 4 compute barriers.
#define IV_OFF   0          // [8*16][52] u16 = 13,312
#define YV_OFF   13312      // 13,312
#define PL_OFF   26624      // [16][264] = 8,448
#define MSK_OFF  35072      // [16][52] = 1,664
#define CNT_OFF  36736      // 64
#define SM3_SIZE 36800
#define SP 52
#define XP 264

__global__ __launch_bounds__(512) void agg_kernel(Params p)
{
    __shared__ __attribute__((aligned(16))) char sm[SM3_SIZE];
    u16t* iv_  = (u16t*)(sm + IV_OFF);
    u16t* yv_  = (u16t*)(sm + YV_OFF);
    u16t* P_l  = (u16t*)(sm + PL_OFF);
    u16t* mskb = (u16t*)(sm + MSK_OFF);
    float* cnt_l = (float*)(sm + CNT_OFF);

    const int bid = blockIdx.x, tid = threadIdx.x;
    const int xcd = bid & 7, idx = bid >> 3;          // idx 0..31
    const int agg = xcd >> 2, xcd_in = xcd & 3;
    const int tg = idx >> 3, b = ((idx & 7) << 2) | xcd_in;
    const int wave = tid >> 6, lane = tid & 63;
    const int l15 = lane & 15, g = lane >> 4;
    const int row_base = b * 48 + tg * 12;

    const float* fb  = agg ? p.sync_fea  : p.async_fea;
    const int*   adj = agg ? p.async_adj : p.sync_adj;
    const u16t* Egb  = p.Eg  + (agg * 32 + b) * 18432;
    const u16t* ETb  = p.ETg + (agg * 32 + b) * 18432;
    const u16t* VTb  = p.VTg + agg * 393216 + b * 12288;

    // ---- masks + passthrough ----
    for (int e = tid; e < 16 * SP; e += 512) {
        int tt = e / SP, k = e - tt * SP;
        u16t v = 0;
        if (tt < 12 && k < 48)
            v = (adj[(b * 48 + k) * 48 + tg * 12 + tt] > 0) ? (u16t)0x3F80 : (u16t)0;
        mskb[e] = v;
    }
    {
        const float4* fb4 = (const float4*)fb;
        float4* out4 = (float4*)p.out;
        for (int e = tid; e < 768; e += 512) {
            int r = e >> 6, c = e & 63;
            out4[(row_base + r) * 256 + 128 + agg * 64 + c] =
                fb4[(row_base + r) * 64 + c];
        }
    }
    __syncthreads();                                             // B1
    if (tid < 12) {
        float c = 0.f;
        for (int s = 0; s < 48; ++s) c += bf2f(mskb[tid * SP + s]);
        cnt_l[tid] = c;
    }

    // ---- Phase A (MFMA): D[row][tt] = sum_k E[row][k]*m[tt][k]; iv = 1/D ----
    #pragma unroll
    for (int jj = 0; jj < 3; ++jj) {
        int rt = wave * 3 + jj;             // 0..23
        const u16t* Arow = Egb + (rt * 16 + l15) * 48;
        const u16t* Brow = mskb + l15 * SP;
        f32x4 acc = {0.f, 0.f, 0.f, 0.f};
        short8v a0 = *(const short8v*)(Arow + g * 8);
        short8v b0 = ld52(Brow + g * 8);
        acc = __builtin_amdgcn_mfma_f32_16x16x32_bf16(a0, b0, acc, 0, 0, 0);
        short8v a1 = {0,0,0,0,0,0,0,0}, b1 = {0,0,0,0,0,0,0,0};
        if (g < 2) { a1 = *(const short8v*)(Arow + 32 + g * 8); b1 = ld52(Brow + 32 + g * 8); }
        acc = __builtin_amdgcn_mfma_f32_16x16x32_bf16(a1, b1, acc, 0, 0, 0);
        #pragma unroll
        for (int i = 0; i < 4; ++i) {
            int row = rt * 16 + g * 4 + i;
            int h = row / 48, q = row - h * 48;
            float mq = bf2f(mskb[l15 * SP + q]);
            float ivv = (mq > 0.f) ? (1.f / acc[i]) : 0.f;
            iv_[(h * 16 + l15) * SP + q] = f2bf(ivv);
        }
    }
    __syncthreads();                                             // B2

    // ---- Phase B (MFMA): yv[tt][h,k] = m[k]*sum_q iv[tt][h,q]*ET[h,k,q] ----
    #pragma unroll
    for (int jj = 0; jj < 3; ++jj) {
        int job = wave * 3 + jj;            // (h, ktile)
        int h = job / 3, kt = job % 3;
        const u16t* Arow = iv_ + (h * 16 + l15) * SP;
        const u16t* Brow = ETb + (h * 48 + kt * 16 + l15) * 48;
        f32x4 acc = {0.f, 0.f, 0.f, 0.f};
        short8v a0 = ld52(Arow + g * 8);
        short8v b0 = *(const short8v*)(Brow + g * 8);
        acc = __builtin_amdgcn_mfma_f32_16x16x32_bf16(a0, b0, acc, 0, 0, 0);
        short8v a1 = {0,0,0,0,0,0,0,0}, b1 = {0,0,0,0,0,0,0,0};
        if (g < 2) { a1 = ld52(Arow + 32 + g * 8); b1 = *(const short8v*)(Brow + 32 + g * 8); }
        acc = __builtin_amdgcn_mfma_f32_16x16x32_bf16(a1, b1, acc, 0, 0, 0);
        #pragma unroll
        for (int i = 0; i < 4; ++i) {
            int tt = g * 4 + i, k = kt * 16 + l15;
            float mk = bf2f(mskb[tt * SP + k]);
            yv_[(h * 16 + tt) * SP + k] = f2bf(acc[i] * mk);
        }
    }
    __syncthreads();                                             // B3

    // ---- Phase C (MFMA): P[tt][d] = sum_k yv[tt][h,k]*VT[b][d][k] (global B) ----
    #pragma unroll
    for (int jj = 0; jj < 2; ++jj) {
        int job = wave * 2 + jj;            // 0..15: (h, dtile)
        int h = job >> 1, dt = job & 1;
        const u16t* Arow = yv_ + (h * 16 + l15) * SP;
        const u16t* Brow = VTb + (h * 32 + dt * 16 + l15) * 48;
        f32x4 acc = {0.f, 0.f, 0.f, 0.f};
        short8v a0 = ld52(Arow + g * 8);
        short8v b0 = *(const short8v*)(Brow + g * 8);
        acc = __builtin_amdgcn_mfma_f32_16x16x32_bf16(a0, b0, acc, 0, 0, 0);
        short8v a1 = {0,0,0,0,0,0,0,0}, b1 = {0,0,0,0,0,0,0,0};
        if (g < 2) { a1 = ld52(Arow + 32 + g * 8); b1 = *(const short8v*)(Brow + 32 + g * 8); }
        acc = __builtin_amdgcn_mfma_f32_16x16x32_bf16(a1, b1, acc, 0, 0, 0);
        #pragma unroll
        for (int i = 0; i < 4; ++i)
            P_l[(g * 4 + i) * XP + h * 32 + dt * 16 + l15] = f2bf(acc[i]);
    }
    __syncthreads();                                             // B4

    // ---- G: out = (P@Wc^T)/cnt^2 + bc/cnt + bm (or fallback) ----
    {
        const u16t* Wc = p.Wcb + agg * 65536;
        const float* bc = p.bcw + agg * 256;
        const float* bm = p.bm_[agg];
        #pragma unroll
        for (int jj = 0; jj < 2; ++jj) {
            int ct = wave * 2 + jj;
            f32x4 acc = {0.f, 0.f, 0.f, 0.f};
            const u16t* Wp = Wc + (ct * 16 + l15) * 256 + g * 8;
            #pragma unroll
            for (int kk = 0; kk < 8; ++kk) {
                short8v a = *(const short8v*)(P_l + l15 * XP + kk * 32 + g * 8);
                short8v bf = *(const short8v*)(Wp + kk * 32);
                acc = __builtin_amdgcn_mfma_f32_16x16x32_bf16(a, bf, acc, 0, 0, 0);
            }
            int c = ct * 16 + l15;
            float bcv = bc[c], bmv = bm[c];
            #pragma unroll
            for (int i = 0; i < 4; ++i) {
                int t = g * 4 + i;
                if (t < 12) {
                    int grow = row_base + t;
                    float cn = cnt_l[t];
                    float val;
                    if (cn > 0.f) {
                        float i1 = 1.f / cn;
                        val = acc[i] * i1 * i1 + bcv * i1 + bmv;
                    } else {
                        val = fb[grow * 256 + c];
                    }
                    p.out[grow * 1024 + agg * 256 + c] = val;
                }
            }
        }
    }
}

extern "C" void kernel_launch(void* const* d_in, const int* in_sizes, int n_in,
                              void* d_out, int out_size, void* d_ws, size_t ws_size,
                              hipStream_t stream)
{
    Params p;
    p.async_fea = (const float*)d_in[0];
    p.sync_fea  = (const float*)d_in[1];
    p.async_adj = (const int*)d_in[2];
    p.sync_adj  = (const int*)d_in[3];
    p.Wq[0] = (const float*)d_in[4];   p.bq[0] = (const float*)d_in[5];
    p.Wk[0] = (const float*)d_in[6];   p.bk[0] = (const float*)d_in[7];
    p.Wv[0] = (const float*)d_in[8];   p.bv[0] = (const float*)d_in[9];
    p.Wo[0] = (const float*)d_in[10];  p.bo_[0] = (const float*)d_in[11];
    p.Wm[0] = (const float*)d_in[12];  p.bm_[0] = (const float*)d_in[13];
    p.Wq[1] = (const float*)d_in[14];  p.bq[1] = (const float*)d_in[15];
    p.Wk[1] = (const float*)d_in[16];  p.bk[1] = (const float*)d_in[17];
    p.Wv[1] = (const float*)d_in[18];  p.bv[1] = (const float*)d_in[19];
    p.Wo[1] = (const float*)d_in[20];  p.bo_[1] = (const float*)d_in[21];
    p.Wm[1] = (const float*)d_in[22];  p.bm_[1] = (const float*)d_in[23];

    u16t* us = (u16t*)d_ws;
    p.Qb  = us;                    // 786,432
    p.Kb  = p.Qb + 786432;         // 786,432
    p.VTg = p.Kb + 786432;         // 786,432
    p.Eg  = p.VTg + 786432;        // 1,179,648
    p.ETg = p.Eg + 1179648;        // 1,179,648
    p.Wcb = p.ETg + 1179648;       // 131,072
    p.bcw = (float*)(p.Wcb + 131072);  // 512 floats
    p.out = (float*)d_out;

    qkv_fold<<<608, 256, 0, stream>>>(p);
    scores_kernel<<<512, 192, 0, stream>>>(p);
    agg_kernel<<<256, 512, 0, stream>>>(p);
}